// Round 4
// baseline (110548.669 us; speedup 1.0000x reference)
//
#include <hip/hip_runtime.h>
#include <math.h>

#define TB 256      // batch
#define TT 512      // timesteps
#define TIN 128     // input size
#define TH 1024     // hidden
#define TOUT 9      // output coords
#define KD 1152     // TIN + TH
#define NT 1024     // k_main block size

// ---- workspace layout (float offsets) ----
#define OFF_WBLK 0ull
#define SZ_WBLK  (256ull*17ull*1152ull)       // per-block weights [w][c][k], c=0..15 gates, 16=out col
#define OFF_WCB  (OFF_WBLK + SZ_WBLK)         // W_combo [9][1024]
#define SZ_WCB   (9ull*1024ull)
#define OFF_BCB  (OFF_WCB + SZ_WCB)           // b_combo [9] (pad 16)
#define SZ_BCB   16ull
#define OFF_B0   (OFF_BCB + SZ_BCB)           // bias t==0 [4096]
#define OFF_BC   (OFF_B0 + 4096ull)           // bias t>0  [4096]
#define OFF_HT0  (OFF_BC + 4096ull)           // h_cell ping, TRANSPOSED [1024 k][256 b]
#define OFF_HT1  (OFF_HT0 + 262144ull)        // h_cell pong
#define OFF_GC   (OFF_HT1 + 262144ull)        // [0]=barrier counter, [1]=abort flag
#define OFF_END  (OFF_GC + 16ull)             // ~22.2 MB total

// ---------------- prep kernels ----------------

// W_combo[r][m] = sum_j W_h2o[r][j]*W_h2h[j][m]; b_combo[r] = W_h2o[r]·b_h2h + b_h2o[r]
__global__ __launch_bounds__(256) void k_combo(const float* __restrict__ W_h2o,
                                               const float* __restrict__ W_h2h,
                                               const float* __restrict__ b_h2h,
                                               const float* __restrict__ b_h2o,
                                               float* __restrict__ Wcombo,
                                               float* __restrict__ bcombo) {
  int gid = blockIdx.x * 256 + threadIdx.x;
  if (gid < 9 * 1024) {
    int r = gid >> 10, m = gid & 1023;
    float s = 0.f;
    for (int j = 0; j < 1024; ++j) s += W_h2o[r * 1024 + j] * W_h2h[j * 1024 + m];
    Wcombo[gid] = s;
  }
  if (gid < 9) {
    float s = b_h2o[gid];
    for (int j = 0; j < 1024; ++j) s += W_h2o[gid * 1024 + j] * b_h2h[j];
    bcombo[gid] = s;
  }
}

// Wh = (W_hh + Wio@W_h2o) @ W_h2h  (A' fused on the fly) -> Wblk[w][c][128+m]
__global__ __launch_bounds__(256) void k_wblk(const float* __restrict__ W_hh,
                                              const float* __restrict__ W_ih,
                                              const float* __restrict__ W_h2o,
                                              const float* __restrict__ W_h2h,
                                              float* __restrict__ Wblk) {
  __shared__ float As2[16][68];
  __shared__ float Bs[16][68];
  __shared__ float Wio_s[64][12];
  __shared__ float Bo[9][16];
  const int tid = threadIdx.x;
  const int bm = (blockIdx.x & 15) * 64;   // m tile
  const int bc = (blockIdx.x >> 4) * 64;   // col tile
  const int tx = tid & 15, ty = tid >> 4;
  const int cl = tid >> 2, kq4 = tid & 3;

  for (int i = tid; i < 64 * 9; i += 256) {
    int row = i / 9, r = i % 9;
    Wio_s[row][r] = W_ih[(size_t)(bc + row) * 137 + 128 + r];
  }

  float acc[4][4];
#pragma unroll
  for (int i = 0; i < 4; ++i)
#pragma unroll
    for (int j = 0; j < 4; ++j) acc[i][j] = 0.f;

  for (int k0 = 0; k0 < 1024; k0 += 16) {
    __syncthreads();   // prior compute done (and Wio_s staged, first iter)
    if (tid < 144) { int r = tid >> 4, kk = tid & 15; Bo[r][kk] = W_h2o[(size_t)r * 1024 + k0 + kk]; }
    { int kk = tid >> 4, q = tid & 15;
      float4 v = *(const float4*)(W_h2h + (size_t)(k0 + kk) * 1024 + bm + q * 4);
      *(float4*)&Bs[kk][q * 4] = v; }
    float4 av = *(const float4*)(W_hh + (size_t)(bc + cl) * 1024 + k0 + kq4 * 4);
    __syncthreads();   // Bo ready
    {
      float c0 = 0.f, c1 = 0.f, c2 = 0.f, c3 = 0.f;
#pragma unroll
      for (int r = 0; r < 9; ++r) {
        float wio = Wio_s[cl][r];
        c0 += wio * Bo[r][kq4 * 4 + 0];
        c1 += wio * Bo[r][kq4 * 4 + 1];
        c2 += wio * Bo[r][kq4 * 4 + 2];
        c3 += wio * Bo[r][kq4 * 4 + 3];
      }
      As2[kq4 * 4 + 0][cl] = av.x + c0;
      As2[kq4 * 4 + 1][cl] = av.y + c1;
      As2[kq4 * 4 + 2][cl] = av.z + c2;
      As2[kq4 * 4 + 3][cl] = av.w + c3;
    }
    __syncthreads();   // As2/Bs ready
#pragma unroll
    for (int kk = 0; kk < 16; ++kk) {
      float4 a = *(const float4*)&As2[kk][ty * 4];
      float4 bv = *(const float4*)&Bs[kk][tx * 4];
      acc[0][0] += a.x * bv.x; acc[0][1] += a.x * bv.y; acc[0][2] += a.x * bv.z; acc[0][3] += a.x * bv.w;
      acc[1][0] += a.y * bv.x; acc[1][1] += a.y * bv.y; acc[1][2] += a.y * bv.z; acc[1][3] += a.y * bv.w;
      acc[2][0] += a.z * bv.x; acc[2][1] += a.z * bv.y; acc[2][2] += a.z * bv.z; acc[2][3] += a.z * bv.w;
      acc[3][0] += a.w * bv.x; acc[3][1] += a.w * bv.y; acc[3][2] += a.w * bv.z; acc[3][3] += a.w * bv.w;
    }
  }
#pragma unroll
  for (int i = 0; i < 4; ++i) {
    int col = bc + ty * 4 + i;
    int q = col >> 10, colh = col & 1023;
    int ww = colh >> 2, c = (q << 2) | (colh & 3);
    float4 v; v.x = acc[i][0]; v.y = acc[i][1]; v.z = acc[i][2]; v.w = acc[i][3];
    *(float4*)(Wblk + ((size_t)ww * 17 + c) * KD + 128 + bm + tx * 4) = v;
  }
}

// biases: b0 = b_ih+b_hh ; bconst = b0 + W_hh·b_h2h + Wio·b_combo
__global__ __launch_bounds__(256) void k_bias(const float* __restrict__ b_ih,
                                              const float* __restrict__ b_hh,
                                              const float* __restrict__ W_hh,
                                              const float* __restrict__ W_ih,
                                              const float* __restrict__ b_h2h,
                                              const float* __restrict__ bcombo,
                                              float* __restrict__ b0,
                                              float* __restrict__ bconst) {
  int col = blockIdx.x * 256 + threadIdx.x;
  float base = b_ih[col] + b_hh[col];
  b0[col] = base;
  float s = 0.f;
  for (int j = 0; j < 1024; ++j) s += W_hh[(size_t)col * 1024 + j] * b_h2h[j];
#pragma unroll
  for (int r = 0; r < 9; ++r) s += W_ih[(size_t)col * 137 + 128 + r] * bcombo[r];
  bconst[col] = base + s;
}

// x-part of Wblk (k<128) and the out column c=16
__global__ __launch_bounds__(256) void k_fillx(const float* __restrict__ W_ih,
                                               const float* __restrict__ Wcombo,
                                               float* __restrict__ Wblk) {
  int gid = blockIdx.x * 256 + threadIdx.x;
  if (gid < 4096 * 128) {
    int col = gid >> 7, k = gid & 127;
    int q = col >> 10, colh = col & 1023;
    int ww = colh >> 2, c = (q << 2) | (colh & 3);
    Wblk[((size_t)ww * 17 + c) * KD + k] = W_ih[(size_t)col * 137 + k];
  }
  int g2 = gid - 4096 * 128;
  if (g2 >= 0 && g2 < 256 * KD) {
    int ww = g2 / KD, k = g2 % KD;
    Wblk[((size_t)ww * 17 + 16) * KD + k] =
        (ww < TOUT && k >= 128) ? Wcombo[(size_t)ww * 1024 + (k - 128)] : 0.f;
  }
}

// lengths passthrough (output 1)
__global__ void k_len(const int* __restrict__ len, float* __restrict__ dout) {
  int i = threadIdx.x;
  if (i < TB) dout[(size_t)TB * TT * TOUT + i] = (float)len[i];
}

// ---------------- main recurrent kernel ----------------
// 256 blocks (1/CU) x 1024 threads (16 waves). Block w owns gate cols
// {q*1024+4w+jj} (locally c=(q<<2)|jj) + out col w (c=16). Weights LDS-resident
// across all 512 steps. kq=tid>>8 (4-way K split, 288 k each), lane = batch b.
// h stored transposed hT[k][b] -> coalesced dword access both directions.

__device__ __forceinline__ float sigm(float v) { return 1.f / (1.f + __expf(-v)); }
__device__ __forceinline__ float tanh_f(float v) {
  float e2 = __expf(2.f * v);
  return (e2 - 1.f) / (e2 + 1.f);
}

__global__ __launch_bounds__(1024, 4) void k_main(const float* __restrict__ x,
                                                  const float* __restrict__ Wblk,
                                                  const float* __restrict__ b0,
                                                  const float* __restrict__ bc,
                                                  const float* __restrict__ bcombo,
                                                  float* __restrict__ hA,
                                                  float* __restrict__ hB,
                                                  unsigned* __restrict__ gcnt,
                                                  float* __restrict__ dout) {
  __shared__ float Wl[17][KD];        // 78,336 B — staged once, reused 512 steps
  __shared__ float red[4][256][17];   // 69,632 B — K-split partials
  __shared__ float bias[2][17];
  __shared__ int sAbort;

  const int w = blockIdx.x;
  const int tid = threadIdx.x;
  const int kq = tid >> 8;
  const int b = tid & 255;

  {  // stage this block's 17x1152 weight slice into LDS (coalesced float4)
    const float4* src = (const float4*)(Wblk + (size_t)w * (17 * KD));
    float4* dst = (float4*)&Wl[0][0];
    for (int i = tid; i < 17 * KD / 4; i += NT) dst[i] = src[i];
  }
  if (tid == 0) sAbort = 0;
  if (tid < 17) {
    int g = (tid >> 2) * 1024 + (w << 2) + (tid & 3);
    bias[0][tid] = (tid < 16) ? b0[g] : 0.f;
    bias[1][tid] = (tid < 16) ? bc[g] : ((w < TOUT) ? bcombo[w] : 0.f);
  }
  float cs = 0.f;   // cell state for (batch fb=tid&255, gate-lane fj=tid>>8)
  __syncthreads();

  const float* ha = hA;   // hT(t-1), zeroed by memset
  float* hn = hB;

  for (int t = 0; t < TT; ++t) {
    float acc[17];
#pragma unroll
    for (int c = 0; c < 17; ++c) acc[c] = 0.f;

    const float* hb = ha + b;
    if (kq == 0) {
      const float4* xp = (const float4*)(x + ((size_t)b * TT + t) * TIN);
#pragma unroll 4
      for (int k4 = 0; k4 < 32; ++k4) {
        float4 a = xp[k4];
#pragma unroll
        for (int c = 0; c < 17; ++c) {
          float4 wv = ((const float4*)&Wl[c][0])[k4];
          acc[c] += a.x * wv.x + a.y * wv.y + a.z * wv.z + a.w * wv.w;
        }
      }
#pragma unroll 4
      for (int u = 0; u < 40; ++u) {
        int k = u * 4;
        float a0 = hb[(size_t)(k + 0) * TB];
        float a1 = hb[(size_t)(k + 1) * TB];
        float a2 = hb[(size_t)(k + 2) * TB];
        float a3 = hb[(size_t)(k + 3) * TB];
#pragma unroll
        for (int c = 0; c < 17; ++c) {
          float4 wv = ((const float4*)&Wl[c][0])[32 + u];
          acc[c] += a0 * wv.x + a1 * wv.y + a2 * wv.z + a3 * wv.w;
        }
      }
    } else {
      const int hk0 = kq * 288 - 128;    // 160, 448, 736
      const int k4g0 = kq * 72;
#pragma unroll 4
      for (int u = 0; u < 72; ++u) {
        int k = hk0 + u * 4;
        float a0 = hb[(size_t)(k + 0) * TB];
        float a1 = hb[(size_t)(k + 1) * TB];
        float a2 = hb[(size_t)(k + 2) * TB];
        float a3 = hb[(size_t)(k + 3) * TB];
#pragma unroll
        for (int c = 0; c < 17; ++c) {
          float4 wv = ((const float4*)&Wl[c][0])[k4g0 + u];
          acc[c] += a0 * wv.x + a1 * wv.y + a2 * wv.z + a3 * wv.w;
        }
      }
    }

#pragma unroll
    for (int c = 0; c < 17; ++c) red[kq][b][c] = acc[c];
    __syncthreads();

    {  // 4-way parallel finish: thread (fb, fj) owns gate-lane fj of batch fb
      const int fb = b;        // tid & 255
      const int fj = kq;       // tid >> 8
      const float* bs = bias[(t > 0) ? 1 : 0];
      float vi = red[0][fb][fj]      + red[1][fb][fj]      + red[2][fb][fj]      + red[3][fb][fj]      + bs[fj];
      float vf = red[0][fb][4 + fj]  + red[1][fb][4 + fj]  + red[2][fb][4 + fj]  + red[3][fb][4 + fj]  + bs[4 + fj];
      float vg = red[0][fb][8 + fj]  + red[1][fb][8 + fj]  + red[2][fb][8 + fj]  + red[3][fb][8 + fj]  + bs[8 + fj];
      float vo = red[0][fb][12 + fj] + red[1][fb][12 + fj] + red[2][fb][12 + fj] + red[3][fb][12 + fj] + bs[12 + fj];
      float ig = sigm(vi), fg = sigm(vf), gg = tanh_f(vg), og = sigm(vo);
      float cn = fg * cs + ig * gg;
      cs = cn;
      hn[(size_t)((w << 2) + fj) * TB + fb] = og * tanh_f(cn);   // transposed, coalesced
      if (fj == 0 && w < TOUT && t > 0) {
        float v16 = red[0][fb][16] + red[1][fb][16] + red[2][fb][16] + red[3][fb][16] + bias[1][16];
        dout[((size_t)fb * TT + (t - 1)) * TOUT + w] = v16;
      }
    }

    // ---- grid barrier: release own stores, signal, spin (bounded), acquire ----
    __threadfence();        // own hn/dout stores visible device-wide
    __syncthreads();        // all threads of block fenced
    if (tid == 0) {
      __hip_atomic_fetch_add(&gcnt[0], 1u, __ATOMIC_ACQ_REL, __HIP_MEMORY_SCOPE_AGENT);
      const unsigned tgt = (unsigned)(t + 1) * 256u;
      int guard = 0;
      while (__hip_atomic_load(&gcnt[0], __ATOMIC_RELAXED, __HIP_MEMORY_SCOPE_AGENT) < tgt) {
        __builtin_amdgcn_s_sleep(2);
        if (__hip_atomic_load(&gcnt[1], __ATOMIC_RELAXED, __HIP_MEMORY_SCOPE_AGENT) != 0u) {
          sAbort = 1; break;                       // someone else timed out
        }
        if (++guard > 65536) {                     // ~10-20 ms cap
          __hip_atomic_store(&gcnt[1], 1u, __ATOMIC_RELEASE, __HIP_MEMORY_SCOPE_AGENT);
          sAbort = 1; break;                       // release the whole grid
        }
      }
    }
    __syncthreads();
    if (sAbort) return;     // wrong answer beats a wedged GPU
    __threadfence();        // acquire: no stale h reads next step

    const float* tp = ha; ha = hn; hn = (float*)tp;
  }

  // ---- epilogue: out(T-1) = h_cell(T-1)·W_combo[w] + b_combo[w] ----
  if (w < TOUT && tid < TB) {
    const float* hb = ha + tid;
    float s = 0.f;
    for (int u = 0; u < 256; ++u) {
      float4 wv = ((const float4*)&Wl[16][0])[32 + u];
      int k = u * 4;
      s += hb[(size_t)(k + 0) * TB] * wv.x + hb[(size_t)(k + 1) * TB] * wv.y
         + hb[(size_t)(k + 2) * TB] * wv.z + hb[(size_t)(k + 3) * TB] * wv.w;
    }
    dout[((size_t)tid * TT + (TT - 1)) * TOUT + w] = s + bias[1][16];
  }
}

// ---------------- launch ----------------

extern "C" void kernel_launch(void* const* d_in, const int* in_sizes, int n_in,
                              void* d_out, int out_size, void* d_ws, size_t ws_size,
                              hipStream_t stream) {
  if (ws_size < (size_t)OFF_END * sizeof(float)) return;   // clean fail, no OOB

  const float* x     = (const float*)d_in[0];
  const float* W_ih  = (const float*)d_in[1];
  const float* b_ih  = (const float*)d_in[2];
  const float* W_hh  = (const float*)d_in[3];
  const float* b_hh  = (const float*)d_in[4];
  const float* W_h2h = (const float*)d_in[5];
  const float* b_h2h = (const float*)d_in[6];
  const float* W_h2o = (const float*)d_in[7];
  const float* b_h2o = (const float*)d_in[8];
  const int*   lens  = (const int*)d_in[9];

  float* wsf    = (float*)d_ws;
  float* dout   = (float*)d_out;
  float* Wblk   = wsf + OFF_WBLK;
  float* Wcombo = wsf + OFF_WCB;
  float* bcombo = wsf + OFF_BCB;
  float* b0     = wsf + OFF_B0;
  float* bconst = wsf + OFF_BC;
  float* hT0    = wsf + OFF_HT0;
  float* hT1    = wsf + OFF_HT1;
  unsigned* gcnt = (unsigned*)(wsf + OFF_GC);

  // zero hT ping-pong + barrier counter + abort flag every call (graph-replay safe)
  hipMemsetAsync((void*)(wsf + OFF_HT0), 0, (size_t)(OFF_END - OFF_HT0) * sizeof(float), stream);

  k_combo<<<36, 256, 0, stream>>>(W_h2o, W_h2h, b_h2h, b_h2o, Wcombo, bcombo);
  k_wblk<<<1024, 256, 0, stream>>>(W_hh, W_ih, W_h2o, W_h2h, Wblk);
  k_bias<<<16, 256, 0, stream>>>(b_ih, b_hh, W_hh, W_ih, b_h2h, bcombo, b0, bconst);
  k_fillx<<<3200, 256, 0, stream>>>(W_ih, Wcombo, Wblk);
  k_len<<<1, 256, 0, stream>>>(lens, dout);

  k_main<<<256, NT, 0, stream>>>(x, Wblk, b0, bconst, bcombo, hT0, hT1, gcnt, dout);
}

// Round 5
// 93543.262 us; speedup vs baseline: 1.1818x; 1.1818x over previous
//
#include <hip/hip_runtime.h>
#include <math.h>

#define TB 256      // batch
#define TT 512      // timesteps
#define TIN 128     // input size
#define TH 1024     // hidden
#define TOUT 9      // output coords
#define KD 1152     // TIN + TH
#define NBLK 256    // k_main grid (2 batch-halves x 128 col-groups)

typedef _Float16 half8 __attribute__((ext_vector_type(8)));
typedef float f32x4 __attribute__((ext_vector_type(4)));

// ---- workspace layout (BYTE offsets) ----
#define OB_WHF   0ull
#define SB_WHF   (128ull*2*36*64*8*2)   // 9,437,184 B  f16 B-fragments [wcg][nt][kc][l][j]
#define OB_WCB   (OB_WHF + SB_WHF)      // Wcombo fp32 [9][1024]
#define SB_WCB   (9ull*1024*4)
#define OB_BCB   (OB_WCB + SB_WCB)      // bcombo fp32 [9] (pad 16)
#define SB_BCB   64ull
#define OB_B0    (OB_BCB + SB_BCB)      // bias t==0 [4096] fp32
#define SB_B0    (4096ull*4)
#define OB_BC    (OB_B0 + SB_B0)        // bias t>0  [4096] fp32
#define SB_BC    (4096ull*4)
#define OB_H0    (OB_BC + SB_BC)        // h_cell ping [256][1024] f16
#define SB_H     (256ull*1024*2)
#define OB_H1    (OB_H0 + SB_H)         // h_cell pong
#define OB_GC    (OB_H1 + SB_H)         // [0]=barrier counter, [1]=abort flag
#define OB_END   (OB_GC + 64ull)        // ~10.1 MB total

// fragment address for gate col `col` (0..4095), k (0..1151):
//   q=col>>10 (gate), hcol=col&1023, wcg=hcol>>3, jj=hcol&7, c=(q<<3)|jj,
//   nt=c>>4, n=c&15, kc=k>>5, ls=(k>>3)&3, je=k&7, lane=(ls<<4)|n
__device__ __forceinline__ size_t frag_addr(int col, int k) {
  int q = col >> 10, hcol = col & 1023;
  int wcg = hcol >> 3, jj = hcol & 7;
  int c = (q << 3) | jj;
  int nt = c >> 4, n = c & 15;
  int kc = k >> 5, ls = (k >> 3) & 3, je = k & 7;
  return ((((size_t)wcg * 2 + nt) * 36 + kc) * 64 + ((ls << 4) | n)) * 8 + je;
}

// ---------------- prep kernels ----------------

// W_combo[r][m] = sum_j W_h2o[r][j]*W_h2h[j][m]; b_combo[r] = W_h2o[r]·b_h2h + b_h2o[r]
__global__ __launch_bounds__(256) void k_combo(const float* __restrict__ W_h2o,
                                               const float* __restrict__ W_h2h,
                                               const float* __restrict__ b_h2h,
                                               const float* __restrict__ b_h2o,
                                               float* __restrict__ Wcombo,
                                               float* __restrict__ bcombo) {
  int gid = blockIdx.x * 256 + threadIdx.x;
  if (gid < 9 * 1024) {
    int r = gid >> 10, m = gid & 1023;
    float s = 0.f;
    for (int j = 0; j < 1024; ++j) s += W_h2o[r * 1024 + j] * W_h2h[j * 1024 + m];
    Wcombo[gid] = s;
  }
  if (gid < 9) {
    float s = b_h2o[gid];
    for (int j = 0; j < 1024; ++j) s += W_h2o[gid * 1024 + j] * b_h2h[j];
    bcombo[gid] = s;
  }
}

// Wh = (W_hh + Wio@W_h2o) @ W_h2h  -> f16 fragments at k=128+m
__global__ __launch_bounds__(256) void k_wblk(const float* __restrict__ W_hh,
                                              const float* __restrict__ W_ih,
                                              const float* __restrict__ W_h2o,
                                              const float* __restrict__ W_h2h,
                                              _Float16* __restrict__ Whf) {
  __shared__ float As2[16][68];
  __shared__ float Bs[16][68];
  __shared__ float Wio_s[64][12];
  __shared__ float Bo[9][16];
  const int tid = threadIdx.x;
  const int bm = (blockIdx.x & 15) * 64;   // m tile
  const int bc = (blockIdx.x >> 4) * 64;   // col tile
  const int tx = tid & 15, ty = tid >> 4;
  const int cl = tid >> 2, kq4 = tid & 3;

  for (int i = tid; i < 64 * 9; i += 256) {
    int row = i / 9, r = i % 9;
    Wio_s[row][r] = W_ih[(size_t)(bc + row) * 137 + 128 + r];
  }

  float acc[4][4];
#pragma unroll
  for (int i = 0; i < 4; ++i)
#pragma unroll
    for (int j = 0; j < 4; ++j) acc[i][j] = 0.f;

  for (int k0 = 0; k0 < 1024; k0 += 16) {
    __syncthreads();
    if (tid < 144) { int r = tid >> 4, kk = tid & 15; Bo[r][kk] = W_h2o[(size_t)r * 1024 + k0 + kk]; }
    { int kk = tid >> 4, q = tid & 15;
      float4 v = *(const float4*)(W_h2h + (size_t)(k0 + kk) * 1024 + bm + q * 4);
      *(float4*)&Bs[kk][q * 4] = v; }
    float4 av = *(const float4*)(W_hh + (size_t)(bc + cl) * 1024 + k0 + kq4 * 4);
    __syncthreads();
    {
      float c0 = 0.f, c1 = 0.f, c2 = 0.f, c3 = 0.f;
#pragma unroll
      for (int r = 0; r < 9; ++r) {
        float wio = Wio_s[cl][r];
        c0 += wio * Bo[r][kq4 * 4 + 0];
        c1 += wio * Bo[r][kq4 * 4 + 1];
        c2 += wio * Bo[r][kq4 * 4 + 2];
        c3 += wio * Bo[r][kq4 * 4 + 3];
      }
      As2[kq4 * 4 + 0][cl] = av.x + c0;
      As2[kq4 * 4 + 1][cl] = av.y + c1;
      As2[kq4 * 4 + 2][cl] = av.z + c2;
      As2[kq4 * 4 + 3][cl] = av.w + c3;
    }
    __syncthreads();
#pragma unroll
    for (int kk = 0; kk < 16; ++kk) {
      float4 a = *(const float4*)&As2[kk][ty * 4];
      float4 bv = *(const float4*)&Bs[kk][tx * 4];
      acc[0][0] += a.x * bv.x; acc[0][1] += a.x * bv.y; acc[0][2] += a.x * bv.z; acc[0][3] += a.x * bv.w;
      acc[1][0] += a.y * bv.x; acc[1][1] += a.y * bv.y; acc[1][2] += a.y * bv.z; acc[1][3] += a.y * bv.w;
      acc[2][0] += a.z * bv.x; acc[2][1] += a.z * bv.y; acc[2][2] += a.z * bv.z; acc[2][3] += a.z * bv.w;
      acc[3][0] += a.w * bv.x; acc[3][1] += a.w * bv.y; acc[3][2] += a.w * bv.z; acc[3][3] += a.w * bv.w;
    }
  }
#pragma unroll
  for (int i = 0; i < 4; ++i)
#pragma unroll
    for (int j = 0; j < 4; ++j) {
      int col = bc + ty * 4 + i;          // gate col
      int m = bm + tx * 4 + j;            // h index -> k = 128+m
      Whf[frag_addr(col, 128 + m)] = (_Float16)acc[i][j];
    }
}

// biases: b0 = b_ih+b_hh ; bconst = b0 + W_hh·b_h2h + Wio·b_combo
__global__ __launch_bounds__(256) void k_bias(const float* __restrict__ b_ih,
                                              const float* __restrict__ b_hh,
                                              const float* __restrict__ W_hh,
                                              const float* __restrict__ W_ih,
                                              const float* __restrict__ b_h2h,
                                              const float* __restrict__ bcombo,
                                              float* __restrict__ b0,
                                              float* __restrict__ bconst) {
  int col = blockIdx.x * 256 + threadIdx.x;
  float base = b_ih[col] + b_hh[col];
  b0[col] = base;
  float s = 0.f;
  for (int j = 0; j < 1024; ++j) s += W_hh[(size_t)col * 1024 + j] * b_h2h[j];
#pragma unroll
  for (int r = 0; r < 9; ++r) s += W_ih[(size_t)col * 137 + 128 + r] * bcombo[r];
  bconst[col] = base + s;
}

// x-part fragments (k<128) from W_ih[:, :128]
__global__ __launch_bounds__(256) void k_fillx(const float* __restrict__ W_ih,
                                               _Float16* __restrict__ Whf) {
  int gid = blockIdx.x * 256 + threadIdx.x;   // 4096*128
  int col = gid >> 7, k = gid & 127;
  Whf[frag_addr(col, k)] = (_Float16)W_ih[(size_t)col * 137 + k];
}

// lengths passthrough (output 1)
__global__ void k_len(const int* __restrict__ len, float* __restrict__ dout) {
  int i = threadIdx.x;
  if (i < TB) dout[(size_t)TB * TT * TOUT + i] = (float)len[i];
}

// ---------------- main recurrent kernel ----------------
// 256 blocks (1/CU) x 1024 thr. Block = (bg = bx>>7 batch-half, wcg = bx&127 col-group).
// Owns batches B0..B0+127, h-cols 8*wcg..+7 (32 gate cols). W f16 fragments LDS-resident.
// Waves: wv=tid>>6 -> (mt = wv&7 M-tile of 16 batches, nt = wv>>3 N-tile of 16 cols).
// Per step: 36 MFMA 16x16x32 f16 per wave; LSTM finish; f16 h write; grid barrier.

__device__ __forceinline__ float sigm(float v) { return 1.f / (1.f + __expf(-v)); }
__device__ __forceinline__ float tanh_f(float v) {
  float e2 = __expf(2.f * v);
  return (e2 - 1.f) / (e2 + 1.f);
}

__global__ __launch_bounds__(1024, 4) void k_main(const float* __restrict__ x,
                                                  const _Float16* __restrict__ Whf,
                                                  const float* __restrict__ Wc,
                                                  const float* __restrict__ b0,
                                                  const float* __restrict__ bcf,
                                                  const float* __restrict__ bcombo,
                                                  _Float16* __restrict__ hA,
                                                  _Float16* __restrict__ hB,
                                                  unsigned* __restrict__ gcnt,
                                                  float* __restrict__ dout) {
  __shared__ _Float16 Wl[2 * 36 * 64 * 8];   // 73,728 B
  __shared__ float gbuf[128][36];            // 18,432 B (pad 36 -> benign 2-way max)
  __shared__ _Float16 htmp[128][8];          //  2,048 B
  __shared__ float obuf[128][9];             //  4,608 B (pad 9)
  __shared__ float bias[2][32];
  __shared__ float sBco;
  __shared__ int sAbort;

  const int bx = blockIdx.x;
  const int wcg = bx & 127;          // col-group: h-cols 8*wcg..+7
  const int B0 = (bx >> 7) * 128;    // batch base
  const int tid = threadIdx.x;
  const int lane = tid & 63;
  const int wv = tid >> 6;
  const int mt = wv & 7, nt2 = wv >> 3;

  {  // stage W fragments (73,728 B) into LDS, coalesced uint4
    const uint4* src = (const uint4*)(Whf + (size_t)wcg * (2 * 36 * 64 * 8));
    uint4* dst = (uint4*)Wl;
    for (int i = tid; i < 2 * 36 * 64 * 8 / 8; i += 1024) dst[i] = src[i];
  }
  if (tid == 0) { sAbort = 0; sBco = (wcg < TOUT) ? bcombo[wcg] : 0.f; }
  if (tid < 32) {
    int g = (tid >> 3) * 1024 + wcg * 8 + (tid & 7);   // c=(q<<3)|jj -> col
    bias[0][tid] = b0[g];
    bias[1][tid] = bcf[g];
  }
  float cs = 0.f;                     // cell state of (batch B0+(tid>>3), h-col 8*wcg+(tid&7))
  __syncthreads();

  const _Float16* ha = hA;            // h_cell(t-1), zeroed
  _Float16* hn = hB;

  const int bA = B0 + mt * 16 + (lane & 15);   // A-fragment batch row
  const int ko = (lane >> 4) * 8;              // A-fragment k offset
  const _Float16* wlbase = Wl + (size_t)nt2 * 36 * 64 * 8 + (size_t)lane * 8;

  for (int t = 0; t < TT; ++t) {
    // ---- MFMA phase: C[128][32] tile, K = 1152 ----
    f32x4 acc = {0.f, 0.f, 0.f, 0.f};
    const float* xrow = x + ((size_t)bA * TT + t) * TIN;
    const _Float16* hrow = ha + (size_t)bA * TH;
#pragma unroll
    for (int kc = 0; kc < 4; ++kc) {           // x part (k<128), convert fp32->f16
      float4 xa = *(const float4*)(xrow + kc * 32 + ko);
      float4 xb = *(const float4*)(xrow + kc * 32 + ko + 4);
      half8 af;
      af[0] = (_Float16)xa.x; af[1] = (_Float16)xa.y; af[2] = (_Float16)xa.z; af[3] = (_Float16)xa.w;
      af[4] = (_Float16)xb.x; af[5] = (_Float16)xb.y; af[6] = (_Float16)xb.z; af[7] = (_Float16)xb.w;
      half8 bf = *(const half8*)(wlbase + (size_t)kc * 64 * 8);
      acc = __builtin_amdgcn_mfma_f32_16x16x32_f16(af, bf, acc, 0, 0, 0);
    }
#pragma unroll 8
    for (int kc = 4; kc < 36; ++kc) {          // h part (k>=128), f16 direct
      half8 af = *(const half8*)(hrow + (kc * 32 - 128 + ko));
      half8 bf = *(const half8*)(wlbase + (size_t)kc * 64 * 8);
      acc = __builtin_amdgcn_mfma_f32_16x16x32_f16(af, bf, acc, 0, 0, 0);
    }
    {  // D layout: col = lane&15, row = (lane>>4)*4 + r
      int rb = mt * 16 + (lane >> 4) * 4;
      int cc = nt2 * 16 + (lane & 15);
      gbuf[rb + 0][cc] = acc[0];
      gbuf[rb + 1][cc] = acc[1];
      gbuf[rb + 2][cc] = acc[2];
      gbuf[rb + 3][cc] = acc[3];
    }

    // ---- out-column partial (blocks wcg<9): out(t-1) = h_cell(t-1)·Wcombo ----
    if (wcg < TOUT) {
      const int fbo = tid & 127, fjo = tid >> 7;          // 8-way K split (128 each)
      const _Float16* hro = ha + (size_t)(B0 + fbo) * TH + fjo * 128;
      const float* wcp = Wc + wcg * 1024 + fjo * 128;     // wave-uniform -> scalar loads
      float s = 0.f;
#pragma unroll 4
      for (int u = 0; u < 16; ++u) {
        half8 hv = *(const half8*)(hro + u * 8);
#pragma unroll
        for (int i2 = 0; i2 < 8; ++i2) s += (float)hv[i2] * wcp[u * 8 + i2];
      }
      obuf[fbo][fjo] = s;
    }
    __syncthreads();

    // ---- LSTM finish: thread owns (fb = tid>>3, fj = tid&7) ----
    {
      const int fb = tid >> 3, fj = tid & 7;
      const float* bs = bias[(t > 0) ? 1 : 0];
      float vi = gbuf[fb][fj]      + bs[fj];
      float vf = gbuf[fb][8 + fj]  + bs[8 + fj];
      float vg = gbuf[fb][16 + fj] + bs[16 + fj];
      float vo = gbuf[fb][24 + fj] + bs[24 + fj];
      float ig = sigm(vi), fg = sigm(vf), gg = tanh_f(vg), og = sigm(vo);
      float cn = fg * cs + ig * gg;
      cs = cn;
      htmp[fb][fj] = (_Float16)(og * tanh_f(cn));
    }
    __syncthreads();

    // ---- writer: coalesced f16 h store + out store ----
    if (tid < 128) {
      uint4 hv = *(const uint4*)&htmp[tid][0];
      *(uint4*)(hn + (size_t)(B0 + tid) * TH + 8 * wcg) = hv;
      if (wcg < TOUT && t > 0) {
        float s = obuf[tid][0] + obuf[tid][1] + obuf[tid][2] + obuf[tid][3]
                + obuf[tid][4] + obuf[tid][5] + obuf[tid][6] + obuf[tid][7] + sBco;
        dout[((size_t)(B0 + tid) * TT + (t - 1)) * TOUT + wcg] = s;
      }
    }

    // ---- hang-proof grid barrier ----
    __threadfence();
    __syncthreads();
    if (tid == 0) {
      __hip_atomic_fetch_add(&gcnt[0], 1u, __ATOMIC_ACQ_REL, __HIP_MEMORY_SCOPE_AGENT);
      const unsigned tgt = (unsigned)(t + 1) * NBLK;
      int guard = 0;
      while (__hip_atomic_load(&gcnt[0], __ATOMIC_RELAXED, __HIP_MEMORY_SCOPE_AGENT) < tgt) {
        __builtin_amdgcn_s_sleep(2);
        if (__hip_atomic_load(&gcnt[1], __ATOMIC_RELAXED, __HIP_MEMORY_SCOPE_AGENT) != 0u) {
          sAbort = 1; break;
        }
        if (++guard > 65536) {
          __hip_atomic_store(&gcnt[1], 1u, __ATOMIC_RELEASE, __HIP_MEMORY_SCOPE_AGENT);
          sAbort = 1; break;
        }
      }
    }
    __syncthreads();
    if (sAbort) return;
    __threadfence();

    const _Float16* tp = ha; ha = hn; hn = (_Float16*)tp;
  }

  // ---- epilogue: out(TT-1) from final h_cell ----
  if (wcg < TOUT) {
    const int fbo = tid & 127, fjo = tid >> 7;
    const _Float16* hro = ha + (size_t)(B0 + fbo) * TH + fjo * 128;
    const float* wcp = Wc + wcg * 1024 + fjo * 128;
    float s = 0.f;
#pragma unroll 4
    for (int u = 0; u < 16; ++u) {
      half8 hv = *(const half8*)(hro + u * 8);
#pragma unroll
      for (int i2 = 0; i2 < 8; ++i2) s += (float)hv[i2] * wcp[u * 8 + i2];
    }
    obuf[fbo][fjo] = s;
  }
  __syncthreads();
  if (wcg < TOUT && tid < 128) {
    float s = obuf[tid][0] + obuf[tid][1] + obuf[tid][2] + obuf[tid][3]
            + obuf[tid][4] + obuf[tid][5] + obuf[tid][6] + obuf[tid][7] + sBco;
    dout[((size_t)(B0 + tid) * TT + (TT - 1)) * TOUT + wcg] = s;
  }
}

// ---------------- launch ----------------

extern "C" void kernel_launch(void* const* d_in, const int* in_sizes, int n_in,
                              void* d_out, int out_size, void* d_ws, size_t ws_size,
                              hipStream_t stream) {
  if (ws_size < OB_END) return;   // clean fail, no OOB

  const float* x     = (const float*)d_in[0];
  const float* W_ih  = (const float*)d_in[1];
  const float* b_ih  = (const float*)d_in[2];
  const float* W_hh  = (const float*)d_in[3];
  const float* b_hh  = (const float*)d_in[4];
  const float* W_h2h = (const float*)d_in[5];
  const float* b_h2h = (const float*)d_in[6];
  const float* W_h2o = (const float*)d_in[7];
  const float* b_h2o = (const float*)d_in[8];
  const int*   lens  = (const int*)d_in[9];

  char* ws = (char*)d_ws;
  float* dout    = (float*)d_out;
  _Float16* Whf  = (_Float16*)(ws + OB_WHF);
  float* Wcombo  = (float*)(ws + OB_WCB);
  float* bcombo  = (float*)(ws + OB_BCB);
  float* b0      = (float*)(ws + OB_B0);
  float* bconst  = (float*)(ws + OB_BC);
  _Float16* h0   = (_Float16*)(ws + OB_H0);
  _Float16* h1   = (_Float16*)(ws + OB_H1);
  unsigned* gcnt = (unsigned*)(ws + OB_GC);

  // zero h ping-pong + barrier counter + abort flag every call (graph-replay safe)
  hipMemsetAsync((void*)(ws + OB_H0), 0, OB_END - OB_H0, stream);

  k_combo<<<36, 256, 0, stream>>>(W_h2o, W_h2h, b_h2h, b_h2o, Wcombo, bcombo);
  k_wblk<<<1024, 256, 0, stream>>>(W_hh, W_ih, W_h2o, W_h2h, Whf);
  k_bias<<<16, 256, 0, stream>>>(b_ih, b_hh, W_hh, W_ih, b_h2h, bcombo, b0, bconst);
  k_fillx<<<2048, 256, 0, stream>>>(W_ih, Whf);
  k_len<<<1, 256, 0, stream>>>(lens, dout);

  k_main<<<NBLK, 1024, 0, stream>>>(x, Whf, Wcombo, b0, bconst, bcombo, h0, h1, gcnt, dout);
}

// Round 6
// 17389.148 us; speedup vs baseline: 6.3573x; 5.3794x over previous
//
#include <hip/hip_runtime.h>
#include <math.h>

#define TB 256      // batch
#define TT 512      // timesteps
#define TIN 128     // input size
#define TH 1024     // hidden
#define TOUT 9      // output coords
#define KD 1152     // TIN + TH

typedef _Float16 half8 __attribute__((ext_vector_type(8)));
typedef float f32x4 __attribute__((ext_vector_type(4)));

// ---- workspace layout (BYTE offsets) ----
#define OB_WHF   0ull
#define SB_WHF   (128ull*2*36*64*8*2)   // 9,437,184 B  f16 B-fragments [wcg][nt][kc][l][j]
#define OB_WCB   (OB_WHF + SB_WHF)      // Wcombo fp32 [9][1024]
#define SB_WCB   (9ull*1024*4)
#define OB_BCB   (OB_WCB + SB_WCB)      // bcombo fp32 [9] (pad 16)
#define SB_BCB   64ull
#define OB_B0    (OB_BCB + SB_BCB)      // bias t==0 [4096] fp32
#define SB_B0    (4096ull*4)
#define OB_BC    (OB_B0 + SB_B0)        // bias t>0  [4096] fp32
#define SB_BC    (4096ull*4)
#define OB_H0    (OB_BC + SB_BC)        // h_cell ping [256][1024] f16
#define SB_H     (256ull*1024*2)
#define OB_H1    (OB_H0 + SB_H)         // h_cell pong
#define OB_CB    (OB_H1 + SB_H)         // cell state fp32 [256][1024]
#define SB_CB    (256ull*1024*4)
#define OB_END   (OB_CB + SB_CB)        // ~11.5 MB total

// fragment address for gate col `col` (0..4095), k (0..1151):
//   q=col>>10 (gate), hcol=col&1023, wcg=hcol>>3, jj=hcol&7, c=(q<<3)|jj,
//   nt=c>>4, n=c&15, kc=k>>5, ls=(k>>3)&3, je=k&7, lane=(ls<<4)|n
__device__ __forceinline__ size_t frag_addr(int col, int k) {
  int q = col >> 10, hcol = col & 1023;
  int wcg = hcol >> 3, jj = hcol & 7;
  int c = (q << 3) | jj;
  int nt = c >> 4, n = c & 15;
  int kc = k >> 5, ls = (k >> 3) & 3, je = k & 7;
  return ((((size_t)wcg * 2 + nt) * 36 + kc) * 64 + ((ls << 4) | n)) * 8 + je;
}

// ---------------- prep kernels (unchanged from round 5, all verified) ----------------

__global__ __launch_bounds__(256) void k_combo(const float* __restrict__ W_h2o,
                                               const float* __restrict__ W_h2h,
                                               const float* __restrict__ b_h2h,
                                               const float* __restrict__ b_h2o,
                                               float* __restrict__ Wcombo,
                                               float* __restrict__ bcombo) {
  int gid = blockIdx.x * 256 + threadIdx.x;
  if (gid < 9 * 1024) {
    int r = gid >> 10, m = gid & 1023;
    float s = 0.f;
    for (int j = 0; j < 1024; ++j) s += W_h2o[r * 1024 + j] * W_h2h[j * 1024 + m];
    Wcombo[gid] = s;
  }
  if (gid < 9) {
    float s = b_h2o[gid];
    for (int j = 0; j < 1024; ++j) s += W_h2o[gid * 1024 + j] * b_h2h[j];
    bcombo[gid] = s;
  }
}

// Wh = (W_hh + Wio@W_h2o) @ W_h2h  -> f16 fragments at k=128+m
__global__ __launch_bounds__(256) void k_wblk(const float* __restrict__ W_hh,
                                              const float* __restrict__ W_ih,
                                              const float* __restrict__ W_h2o,
                                              const float* __restrict__ W_h2h,
                                              _Float16* __restrict__ Whf) {
  __shared__ float As2[16][68];
  __shared__ float Bs[16][68];
  __shared__ float Wio_s[64][12];
  __shared__ float Bo[9][16];
  const int tid = threadIdx.x;
  const int bm = (blockIdx.x & 15) * 64;   // m tile
  const int bc = (blockIdx.x >> 4) * 64;   // col tile
  const int tx = tid & 15, ty = tid >> 4;
  const int cl = tid >> 2, kq4 = tid & 3;

  for (int i = tid; i < 64 * 9; i += 256) {
    int row = i / 9, r = i % 9;
    Wio_s[row][r] = W_ih[(size_t)(bc + row) * 137 + 128 + r];
  }

  float acc[4][4];
#pragma unroll
  for (int i = 0; i < 4; ++i)
#pragma unroll
    for (int j = 0; j < 4; ++j) acc[i][j] = 0.f;

  for (int k0 = 0; k0 < 1024; k0 += 16) {
    __syncthreads();
    if (tid < 144) { int r = tid >> 4, kk = tid & 15; Bo[r][kk] = W_h2o[(size_t)r * 1024 + k0 + kk]; }
    { int kk = tid >> 4, q = tid & 15;
      float4 v = *(const float4*)(W_h2h + (size_t)(k0 + kk) * 1024 + bm + q * 4);
      *(float4*)&Bs[kk][q * 4] = v; }
    float4 av = *(const float4*)(W_hh + (size_t)(bc + cl) * 1024 + k0 + kq4 * 4);
    __syncthreads();
    {
      float c0 = 0.f, c1 = 0.f, c2 = 0.f, c3 = 0.f;
#pragma unroll
      for (int r = 0; r < 9; ++r) {
        float wio = Wio_s[cl][r];
        c0 += wio * Bo[r][kq4 * 4 + 0];
        c1 += wio * Bo[r][kq4 * 4 + 1];
        c2 += wio * Bo[r][kq4 * 4 + 2];
        c3 += wio * Bo[r][kq4 * 4 + 3];
      }
      As2[kq4 * 4 + 0][cl] = av.x + c0;
      As2[kq4 * 4 + 1][cl] = av.y + c1;
      As2[kq4 * 4 + 2][cl] = av.z + c2;
      As2[kq4 * 4 + 3][cl] = av.w + c3;
    }
    __syncthreads();
#pragma unroll
    for (int kk = 0; kk < 16; ++kk) {
      float4 a = *(const float4*)&As2[kk][ty * 4];
      float4 bv = *(const float4*)&Bs[kk][tx * 4];
      acc[0][0] += a.x * bv.x; acc[0][1] += a.x * bv.y; acc[0][2] += a.x * bv.z; acc[0][3] += a.x * bv.w;
      acc[1][0] += a.y * bv.x; acc[1][1] += a.y * bv.y; acc[1][2] += a.y * bv.z; acc[1][3] += a.y * bv.w;
      acc[2][0] += a.z * bv.x; acc[2][1] += a.z * bv.y; acc[2][2] += a.z * bv.z; acc[2][3] += a.z * bv.w;
      acc[3][0] += a.w * bv.x; acc[3][1] += a.w * bv.y; acc[3][2] += a.w * bv.z; acc[3][3] += a.w * bv.w;
    }
  }
#pragma unroll
  for (int i = 0; i < 4; ++i)
#pragma unroll
    for (int j = 0; j < 4; ++j) {
      int col = bc + ty * 4 + i;          // gate col
      int m = bm + tx * 4 + j;            // h index -> k = 128+m
      Whf[frag_addr(col, 128 + m)] = (_Float16)acc[i][j];
    }
}

__global__ __launch_bounds__(256) void k_bias(const float* __restrict__ b_ih,
                                              const float* __restrict__ b_hh,
                                              const float* __restrict__ W_hh,
                                              const float* __restrict__ W_ih,
                                              const float* __restrict__ b_h2h,
                                              const float* __restrict__ bcombo,
                                              float* __restrict__ b0,
                                              float* __restrict__ bconst) {
  int col = blockIdx.x * 256 + threadIdx.x;
  float base = b_ih[col] + b_hh[col];
  b0[col] = base;
  float s = 0.f;
  for (int j = 0; j < 1024; ++j) s += W_hh[(size_t)col * 1024 + j] * b_h2h[j];
#pragma unroll
  for (int r = 0; r < 9; ++r) s += W_ih[(size_t)col * 137 + 128 + r] * bcombo[r];
  bconst[col] = base + s;
}

__global__ __launch_bounds__(256) void k_fillx(const float* __restrict__ W_ih,
                                               _Float16* __restrict__ Whf) {
  int gid = blockIdx.x * 256 + threadIdx.x;   // 4096*128
  int col = gid >> 7, k = gid & 127;
  Whf[frag_addr(col, k)] = (_Float16)W_ih[(size_t)col * 137 + k];
}

__global__ void k_len(const int* __restrict__ len, float* __restrict__ dout) {
  int i = threadIdx.x;
  if (i < TB) dout[(size_t)TB * TT * TOUT + i] = (float)len[i];
}

// ---------------- per-timestep kernel ----------------
// Launched TT times; kernel boundary = device-wide barrier + coherence (no
// software barrier, no fences, no atomics). 256 blocks x 1024 thr, 1/CU.
// Block = (batch-half bx>>7, col-group wcg=bx&127 owning h-cols 8wcg..+7).
// Per step: stage 73KB W-fragments to LDS, 36 MFMA 16x16x32 f16 per wave,
// LSTM finish (cell state in global cbuf), f16 h write, out(t-1) for wcg<9.

__device__ __forceinline__ float sigm(float v) { return 1.f / (1.f + __expf(-v)); }
__device__ __forceinline__ float tanh_f(float v) {
  float e2 = __expf(2.f * v);
  return (e2 - 1.f) / (e2 + 1.f);
}

__global__ __launch_bounds__(1024, 1) void k_step(const float* __restrict__ x,
                                                  const _Float16* __restrict__ Whf,
                                                  const float* __restrict__ Wc,
                                                  const float* __restrict__ bias_g,
                                                  const float* __restrict__ bcombo,
                                                  const _Float16* __restrict__ ha,
                                                  _Float16* __restrict__ hn,
                                                  float* __restrict__ cbuf,
                                                  float* __restrict__ dout,
                                                  int t) {
  __shared__ _Float16 Wl[2 * 36 * 64 * 8];   // 73,728 B
  __shared__ float gbuf[128][36];            // 18,432 B
  __shared__ _Float16 htmp[128][8];          //  2,048 B
  __shared__ float obuf[128][9];             //  4,608 B
  __shared__ float bias_s[32];
  __shared__ float sBco;

  const int bx = blockIdx.x;
  const int wcg = bx & 127;          // col-group: h-cols 8*wcg..+7
  const int B0 = (bx >> 7) * 128;    // batch base
  const int tid = threadIdx.x;
  const int lane = tid & 63;
  const int wv = tid >> 6;
  const int mt = wv & 7, nt2 = wv >> 3;

  {  // stage this col-group's W fragments into LDS (hot in XCD L2 across launches)
    const uint4* src = (const uint4*)(Whf + (size_t)wcg * (2 * 36 * 64 * 8));
    uint4* dst = (uint4*)Wl;
    for (int i = tid; i < 2 * 36 * 64 * 8 / 8; i += 1024) dst[i] = src[i];
  }
  if (tid == 0) sBco = (wcg < TOUT) ? bcombo[wcg] : 0.f;
  if (tid < 32) {
    int g = (tid >> 3) * 1024 + wcg * 8 + (tid & 7);   // c=(q<<3)|jj -> gate col
    bias_s[tid] = bias_g[g];
  }

  const int bA = B0 + mt * 16 + (lane & 15);   // A-fragment batch row
  const int ko = (lane >> 4) * 8;              // A-fragment k offset
  const _Float16* wlbase = Wl + (size_t)nt2 * 36 * 64 * 8 + (size_t)lane * 8;
  const float* xrow = x + ((size_t)bA * TT + t) * TIN;
  const _Float16* hrow = ha + (size_t)bA * TH;

  __syncthreads();

  // ---- MFMA phase: C[128][32] tile, K = 1152, 2 accumulators ----
  f32x4 acc0 = {0.f, 0.f, 0.f, 0.f};
  f32x4 acc1 = {0.f, 0.f, 0.f, 0.f};
#pragma unroll
  for (int kc = 0; kc < 4; ++kc) {             // x part (k<128), convert fp32->f16
    float4 xa = *(const float4*)(xrow + kc * 32 + ko);
    float4 xb = *(const float4*)(xrow + kc * 32 + ko + 4);
    half8 af;
    af[0] = (_Float16)xa.x; af[1] = (_Float16)xa.y; af[2] = (_Float16)xa.z; af[3] = (_Float16)xa.w;
    af[4] = (_Float16)xb.x; af[5] = (_Float16)xb.y; af[6] = (_Float16)xb.z; af[7] = (_Float16)xb.w;
    half8 bf = *(const half8*)(wlbase + (size_t)kc * 64 * 8);
    if (kc & 1) acc1 = __builtin_amdgcn_mfma_f32_16x16x32_f16(af, bf, acc1, 0, 0, 0);
    else        acc0 = __builtin_amdgcn_mfma_f32_16x16x32_f16(af, bf, acc0, 0, 0, 0);
  }
#pragma unroll 8
  for (int kc = 4; kc < 36; ++kc) {            // h part (k>=128), f16 direct
    half8 af = *(const half8*)(hrow + (kc * 32 - 128 + ko));
    half8 bf = *(const half8*)(wlbase + (size_t)kc * 64 * 8);
    if (kc & 1) acc1 = __builtin_amdgcn_mfma_f32_16x16x32_f16(af, bf, acc1, 0, 0, 0);
    else        acc0 = __builtin_amdgcn_mfma_f32_16x16x32_f16(af, bf, acc0, 0, 0, 0);
  }
  {  // D layout: col = lane&15, row = (lane>>4)*4 + r
    f32x4 acc = acc0 + acc1;
    int rb = mt * 16 + (lane >> 4) * 4;
    int cc = nt2 * 16 + (lane & 15);
    gbuf[rb + 0][cc] = acc[0];
    gbuf[rb + 1][cc] = acc[1];
    gbuf[rb + 2][cc] = acc[2];
    gbuf[rb + 3][cc] = acc[3];
  }

  // ---- out-column partial (blocks wcg<9): out(t-1) = h_cell(t-1)·Wcombo ----
  if (wcg < TOUT && t > 0) {
    const int fbo = tid & 127, fjo = tid >> 7;          // 8-way K split (128 each)
    const _Float16* hro = ha + (size_t)(B0 + fbo) * TH + fjo * 128;
    const float* wcp = Wc + wcg * 1024 + fjo * 128;     // wave-uniform -> scalar loads
    float s = 0.f;
#pragma unroll 4
    for (int u = 0; u < 16; ++u) {
      half8 hv = *(const half8*)(hro + u * 8);
#pragma unroll
      for (int i2 = 0; i2 < 8; ++i2) s += (float)hv[i2] * wcp[u * 8 + i2];
    }
    obuf[fbo][fjo] = s;
  }
  __syncthreads();

  // ---- LSTM finish: thread owns (fb = tid>>3, fj = tid&7); c state in global ----
  {
    const int fb = tid >> 3, fj = tid & 7;
    float* cptr = cbuf + (size_t)(B0 + fb) * TH + wcg * 8 + fj;
    float vi = gbuf[fb][fj]      + bias_s[fj];
    float vf = gbuf[fb][8 + fj]  + bias_s[8 + fj];
    float vg = gbuf[fb][16 + fj] + bias_s[16 + fj];
    float vo = gbuf[fb][24 + fj] + bias_s[24 + fj];
    float ig = sigm(vi), fg = sigm(vf), gg = tanh_f(vg), og = sigm(vo);
    float cn = fg * (*cptr) + ig * gg;
    *cptr = cn;
    htmp[fb][fj] = (_Float16)(og * tanh_f(cn));
  }
  __syncthreads();

  // ---- writer: coalesced f16 h store + out store ----
  if (tid < 128) {
    uint4 hv = *(const uint4*)&htmp[tid][0];
    *(uint4*)(hn + (size_t)(B0 + tid) * TH + 8 * wcg) = hv;
    if (wcg < TOUT && t > 0) {
      float s = obuf[tid][0] + obuf[tid][1] + obuf[tid][2] + obuf[tid][3]
              + obuf[tid][4] + obuf[tid][5] + obuf[tid][6] + obuf[tid][7] + sBco;
      dout[((size_t)(B0 + tid) * TT + (t - 1)) * TOUT + wcg] = s;
    }
  }
}

// epilogue: out(TT-1) = h_cell(TT-1)·Wcombo + bcombo
__global__ __launch_bounds__(256) void k_last(const _Float16* __restrict__ hfin,
                                              const float* __restrict__ Wc,
                                              const float* __restrict__ bcombo,
                                              float* __restrict__ dout) {
  const int w = blockIdx.x;      // 0..8
  const int b = threadIdx.x;     // 0..255
  const _Float16* hr = hfin + (size_t)b * TH;
  const float* wcp = Wc + w * 1024;
  float s = 0.f;
#pragma unroll 8
  for (int u = 0; u < 128; ++u) {
    half8 hv = *(const half8*)(hr + u * 8);
#pragma unroll
    for (int i2 = 0; i2 < 8; ++i2) s += (float)hv[i2] * wcp[u * 8 + i2];
  }
  dout[((size_t)b * TT + (TT - 1)) * TOUT + w] = s + bcombo[w];
}

// ---------------- launch ----------------

extern "C" void kernel_launch(void* const* d_in, const int* in_sizes, int n_in,
                              void* d_out, int out_size, void* d_ws, size_t ws_size,
                              hipStream_t stream) {
  if (ws_size < OB_END) return;   // clean fail, no OOB

  const float* x     = (const float*)d_in[0];
  const float* W_ih  = (const float*)d_in[1];
  const float* b_ih  = (const float*)d_in[2];
  const float* W_hh  = (const float*)d_in[3];
  const float* b_hh  = (const float*)d_in[4];
  const float* W_h2h = (const float*)d_in[5];
  const float* b_h2h = (const float*)d_in[6];
  const float* W_h2o = (const float*)d_in[7];
  const float* b_h2o = (const float*)d_in[8];
  const int*   lens  = (const int*)d_in[9];

  char* ws = (char*)d_ws;
  float* dout    = (float*)d_out;
  _Float16* Whf  = (_Float16*)(ws + OB_WHF);
  float* Wcombo  = (float*)(ws + OB_WCB);
  float* bcombo  = (float*)(ws + OB_BCB);
  float* b0      = (float*)(ws + OB_B0);
  float* bconst  = (float*)(ws + OB_BC);
  _Float16* h0   = (_Float16*)(ws + OB_H0);
  _Float16* h1   = (_Float16*)(ws + OB_H1);
  float* cbuf    = (float*)(ws + OB_CB);

  // zero h ping-pong + cell state every call (graph-replay safe)
  hipMemsetAsync((void*)(ws + OB_H0), 0, OB_END - OB_H0, stream);

  k_combo<<<36, 256, 0, stream>>>(W_h2o, W_h2h, b_h2h, b_h2o, Wcombo, bcombo);
  k_wblk<<<1024, 256, 0, stream>>>(W_hh, W_ih, W_h2o, W_h2h, Whf);
  k_bias<<<16, 256, 0, stream>>>(b_ih, b_hh, W_hh, W_ih, b_h2h, bcombo, b0, bconst);
  k_fillx<<<2048, 256, 0, stream>>>(W_ih, Whf);
  k_len<<<1, 256, 0, stream>>>(lens, dout);

  // 512 per-step launches: kernel boundary = device barrier + coherence
  for (int t = 0; t < TT; ++t) {
    const float* bsel = (t == 0) ? b0 : bconst;
    const _Float16* src = (t & 1) ? h1 : h0;
    _Float16* dst = (t & 1) ? h0 : h1;
    k_step<<<256, 1024, 0, stream>>>(x, Whf, Wcombo, bsel, bcombo, src, dst, cbuf, dout, t);
  }
  // final h is in h0 (after t=511 writes h0)
  k_last<<<TOUT, 256, 0, stream>>>(h0, Wcombo, bcombo, dout);
}